// Round 8
// baseline (710.807 us; speedup 1.0000x reference)
//
#include <hip/hip_runtime.h>
#include <hip/hip_cooperative_groups.h>

namespace cg = cooperative_groups;

// ---------------------------------------------------------------------------
// GraphSAGE 3-layer encoder. N=50000, E=640000, ch 32 -> 64 -> 128 -> 64.
// R8: ONE cooperative mega-kernel (grid.sync between phases) replaces the
// 10-dispatch serial chain -> removes ~8 launch gaps. Phases: prep+zero,
// count, scan a/b, fill, L1 fused gather+MFMA, L2 fused, L3 dual GEMM,
// final gather+add. Weights read from L2-hot wprep (no LDS staging);
// LDS = one 64x68 f32 tile (17.4KB) -> >=4 blocks/CU with lb(256,4).
// GEMM math: split-bf16 MFMA (hi*hi + hi*lo + lo*hi, fp32 acc).
// ---------------------------------------------------------------------------

typedef short bf8 __attribute__((ext_vector_type(8)));   // 8 bf16 in 4 VGPR
typedef float f32x4 __attribute__((ext_vector_type(4)));

__device__ inline ushort bf16rn(float f) {               // round-to-nearest-even
    unsigned u = __float_as_uint(f);
    return (ushort)((u + 0x7FFFu + ((u >> 16) & 1u)) >> 16);
}
__device__ inline float bf16tof(ushort h) {
    return __uint_as_float(((unsigned)h) << 16);
}
__device__ inline void split8(const float4 pa, const float4 pb, bf8& hi, bf8& lo) {
    const float v[8] = {pa.x, pa.y, pa.z, pa.w, pb.x, pb.y, pb.z, pb.w};
#pragma unroll
    for (int j = 0; j < 8; ++j) {
        const ushort h = bf16rn(v[j]);
        hi[j] = (short)h;
        lo[j] = (short)bf16rn(v[j] - bf16tof(h));
    }
}

__global__ __launch_bounds__(256, 4) void mega_kernel(
    const float* __restrict__ x, const int* __restrict__ ei,
    const float* __restrict__ w1l, const float* __restrict__ b1,
    const float* __restrict__ w1r,
    const float* __restrict__ w2l, const float* __restrict__ b2,
    const float* __restrict__ w2r,
    const float* __restrict__ w3l, const float* __restrict__ b3,
    const float* __restrict__ w3r,
    float* __restrict__ dout,
    int* cnt, int* cursor, int* partials, int* rowptr, int* csr_src,
    ushort* wprep, float* h1, float* h2, float* r3,
    int nN, int nE)
{
    __shared__ float tile[64 * 68];     // L2 tile is the max (17408 B)
    __shared__ int ssc[4];

    cg::grid_group grid = cg::this_grid();

    const int tid = threadIdx.x;
    const int bid = blockIdx.x;
    const int nblk = gridDim.x;
    const int gthr = bid * 256 + tid;
    const int nthr = nblk * 256;
    const int* src = ei;
    const int* dst = ei + nE;
    const int nSB = (nN + 1023) >> 10;
    const int ntiles = (nN + 63) >> 6;
    float* t3 = h1;                      // h1 dead after phase 5

    // ============ phase 0: weight prep (9216 frags) + zero cnt/cursor ======
    for (int f = gthr; f < 9216; f += nthr) {
        int base, KCs, oc0, d0, wstride;
        const float *wa, *wb;
        if (f < 1024)      { base = 0;    KCs = 2; oc0 = 0;  wa = w1l; wb = w1r; d0 = 32;  wstride = 64;  }
        else if (f < 3072) { base = 1024; KCs = 4; oc0 = 0;  wa = w2l; wb = w2r; d0 = 64;  wstride = 128; }
        else if (f < 5120) { base = 3072; KCs = 4; oc0 = 64; wa = w2l; wb = w2r; d0 = 64;  wstride = 128; }
        else if (f < 7168) { base = 5120; KCs = 4; oc0 = 0;  wa = w3l; wb = w3l; d0 = 128; wstride = 64;  }
        else               { base = 7168; KCs = 4; oc0 = 0;  wa = w3r; wb = w3r; d0 = 128; wstride = 64;  }
        const int local = f - base;
        const int lane = local & 63;
        const int s = (local >> 6) & 1;
        const int kcct = local >> 7;
        const int kc = kcct % KCs;
        const int ct = kcct / KCs;
        const int col = oc0 + ct * 16 + (lane & 15);
        const int k0 = kc * 32 + (lane >> 4) * 8;
        ushort h8[8];
#pragma unroll
        for (int j = 0; j < 8; ++j) {
            const int k = k0 + j;
            const float* wr = (k < d0) ? (wa + (size_t)k * wstride)
                                       : (wb + (size_t)(k - d0) * wstride);
            const float v = wr[col];
            const ushort h = bf16rn(v);
            h8[j] = (s == 0) ? h : bf16rn(v - bf16tof(h));
        }
        *reinterpret_cast<int4*>(wprep + (size_t)f * 8) = *reinterpret_cast<const int4*>(h8);
    }
    for (int i = gthr; i < 2 * nN + 64; i += nthr) cnt[i] = 0;   // covers cursor
    grid.sync();

    // ============ phase 1: count ==========================================
    {
        const int n4 = nE >> 2;
        for (int i = gthr; i < n4; i += nthr) {
            const int4 d = reinterpret_cast<const int4*>(dst)[i];
            atomicAdd(&cnt[d.x], 1);
            atomicAdd(&cnt[d.y], 1);
            atomicAdd(&cnt[d.z], 1);
            atomicAdd(&cnt[d.w], 1);
        }
        for (int e = (nE & ~3) + gthr; e < nE; e += nthr)
            atomicAdd(&cnt[dst[e]], 1);
    }
    grid.sync();

    // ============ phase 2a: per-1024 block exclusive scan =================
    for (int b = bid; b < nSB; b += nblk) {
        const int lane = tid & 63, wid = tid >> 6;
        const int base = b * 1024 + tid * 4;
        int4 v = make_int4(0, 0, 0, 0);
        if (base + 3 < nN) {
            v = *reinterpret_cast<const int4*>(cnt + base);
        } else {
            if (base + 0 < nN) v.x = cnt[base + 0];
            if (base + 1 < nN) v.y = cnt[base + 1];
            if (base + 2 < nN) v.z = cnt[base + 2];
            if (base + 3 < nN) v.w = cnt[base + 3];
        }
        const int s = v.x + v.y + v.z + v.w;
        int inc = s;
#pragma unroll
        for (int d = 1; d < 64; d <<= 1) {
            int u = __shfl_up(inc, d);
            if (lane >= d) inc += u;
        }
        if (lane == 63) ssc[wid] = inc;
        __syncthreads();
        int woff = 0;
#pragma unroll
        for (int w = 0; w < 4; ++w) woff += (w < wid) ? ssc[w] : 0;
        const int excl = woff + inc - s;
        int4 o;
        o.x = excl; o.y = excl + v.x; o.z = excl + v.x + v.y; o.w = excl + v.x + v.y + v.z;
        if (base + 3 < nN) {
            *reinterpret_cast<int4*>(rowptr + base) = o;
        } else {
            if (base + 0 < nN) rowptr[base + 0] = o.x;
            if (base + 1 < nN) rowptr[base + 1] = o.y;
            if (base + 2 < nN) rowptr[base + 2] = o.z;
            if (base + 3 < nN) rowptr[base + 3] = o.w;
        }
        if (tid == 255) partials[b] = woff + inc;
        __syncthreads();
    }
    grid.sync();

    // ============ phase 2b: add block offsets =============================
    for (int b = bid; b < nSB; b += nblk) {
        if (tid < 64) {
            int v = (tid < b) ? partials[tid] : 0;    // nSB <= 64
#pragma unroll
            for (int d = 32; d >= 1; d >>= 1) v += __shfl_xor(v, d);
            if (tid == 0) ssc[0] = v;
        }
        __syncthreads();
        const int off = ssc[0];
        const int base = b * 1024 + tid * 4;
        if (base + 3 < nN) {
            int4 v = *reinterpret_cast<int4*>(rowptr + base);
            v.x += off; v.y += off; v.z += off; v.w += off;
            *reinterpret_cast<int4*>(rowptr + base) = v;
        } else {
            if (base + 0 < nN) rowptr[base + 0] += off;
            if (base + 1 < nN) rowptr[base + 1] += off;
            if (base + 2 < nN) rowptr[base + 2] += off;
            if (base + 3 < nN) rowptr[base + 3] += off;
        }
        __syncthreads();
    }
    if (gthr == 0) rowptr[nN] = nE;
    grid.sync();

    // ============ phase 3: fill ===========================================
    {
        const int n4 = nE >> 2;
        for (int i = gthr; i < n4; i += nthr) {
            const int4 s4 = reinterpret_cast<const int4*>(src)[i];
            const int4 d4 = reinterpret_cast<const int4*>(dst)[i];
            int p0 = atomicAdd(&cursor[d4.x], 1); csr_src[rowptr[d4.x] + p0] = s4.x;
            int p1 = atomicAdd(&cursor[d4.y], 1); csr_src[rowptr[d4.y] + p1] = s4.y;
            int p2 = atomicAdd(&cursor[d4.z], 1); csr_src[rowptr[d4.z] + p2] = s4.z;
            int p3 = atomicAdd(&cursor[d4.w], 1); csr_src[rowptr[d4.w] + p3] = s4.w;
        }
        for (int e = (nE & ~3) + gthr; e < nE; e += nthr) {
            int d = dst[e];
            int pos = atomicAdd(&cursor[d], 1);
            csr_src[rowptr[d] + pos] = src[e];
        }
    }
    grid.sync();

    // ============ phase 4: layer 1 fused (D0=32) ==========================
    for (int tix = bid; tix < ntiles; tix += nblk) {
        const int node0 = tix * 64;
        {   // gather mean(x) -> tile[64][36]
            const float4* x4 = reinterpret_cast<const float4*>(x);
            const int c = tid & 7;
            const int nl0 = tid >> 3;
#pragma unroll
            for (int p = 0; p < 2; ++p) {
                const int nl = p * 32 + nl0;
                const int node = node0 + nl;
                float4 acc = make_float4(0.f, 0.f, 0.f, 0.f);
                if (node < nN) {
                    const int beg = rowptr[node], end = rowptr[node + 1];
                    int e = beg;
                    for (; e + 7 < end; e += 8) {
                        int si[8];
#pragma unroll
                        for (int j = 0; j < 8; ++j) si[j] = csr_src[e + j];
                        float4 v[8];
#pragma unroll
                        for (int j = 0; j < 8; ++j) v[j] = x4[(size_t)si[j] * 8 + c];
                        acc.x += ((v[0].x + v[1].x) + (v[2].x + v[3].x)) + ((v[4].x + v[5].x) + (v[6].x + v[7].x));
                        acc.y += ((v[0].y + v[1].y) + (v[2].y + v[3].y)) + ((v[4].y + v[5].y) + (v[6].y + v[7].y));
                        acc.z += ((v[0].z + v[1].z) + (v[2].z + v[3].z)) + ((v[4].z + v[5].z) + (v[6].z + v[7].z));
                        acc.w += ((v[0].w + v[1].w) + (v[2].w + v[3].w)) + ((v[4].w + v[5].w) + (v[6].w + v[7].w));
                    }
                    for (; e < end; ++e) {
                        int s0 = csr_src[e];
                        float4 v0 = x4[(size_t)s0 * 8 + c];
                        acc.x += v0.x; acc.y += v0.y; acc.z += v0.z; acc.w += v0.w;
                    }
                    const float sc = 1.0f / (float)max(end - beg, 1);
                    acc.x *= sc; acc.y *= sc; acc.z *= sc; acc.w *= sc;
                }
                *reinterpret_cast<float4*>(&tile[nl * 36 + c * 4]) = acc;
            }
        }
        __syncthreads();
        {   // MFMA 64x64, K=64
            const int w = tid >> 6, lane = tid & 63;
            const int rloc = w * 16 + (lane & 15);
            const int arow = min(node0 + rloc, nN - 1);
            const int kg = lane >> 4;
            bf8 ahi[2], alo[2];
            {
                const float* tp = &tile[rloc * 36 + kg * 8];
                split8(*reinterpret_cast<const float4*>(tp),
                       *reinterpret_cast<const float4*>(tp + 4), ahi[0], alo[0]);
            }
            {
                const float* rp = x + (size_t)arow * 32 + kg * 8;
                split8(*reinterpret_cast<const float4*>(rp),
                       *reinterpret_cast<const float4*>(rp + 4), ahi[1], alo[1]);
            }
            const bf8* bgl = reinterpret_cast<const bf8*>(wprep);
#pragma unroll
            for (int ct = 0; ct < 4; ++ct) {
                f32x4 acc = {0.f, 0.f, 0.f, 0.f};
#pragma unroll
                for (int kc = 0; kc < 2; ++kc) {
                    const bf8 bhi = bgl[((ct * 2 + kc) * 2 + 0) * 64 + lane];
                    const bf8 blo = bgl[((ct * 2 + kc) * 2 + 1) * 64 + lane];
                    acc = __builtin_amdgcn_mfma_f32_16x16x32_bf16(ahi[kc], bhi, acc, 0, 0, 0);
                    acc = __builtin_amdgcn_mfma_f32_16x16x32_bf16(ahi[kc], blo, acc, 0, 0, 0);
                    acc = __builtin_amdgcn_mfma_f32_16x16x32_bf16(alo[kc], bhi, acc, 0, 0, 0);
                }
                const int col = ct * 16 + (lane & 15);
                const float bv = b1[col];
#pragma unroll
                for (int r = 0; r < 4; ++r) {
                    const int node = node0 + w * 16 + (lane >> 4) * 4 + r;
                    if (node < nN) h1[(size_t)node * 64 + col] = fmaxf(acc[r] + bv, 0.f);
                }
            }
        }
        __syncthreads();
    }
    grid.sync();

    // ============ phase 5: layer 2 fused (D0=64) ==========================
    for (int tix = bid; tix < ntiles; tix += nblk) {
        const int node0 = tix * 64;
        {   // gather mean(h1) -> tile[64][68]
            const float4* x4 = reinterpret_cast<const float4*>(h1);
            const int c = tid & 15;
            const int nl0 = tid >> 4;
#pragma unroll
            for (int p = 0; p < 4; ++p) {
                const int nl = p * 16 + nl0;
                const int node = node0 + nl;
                float4 acc = make_float4(0.f, 0.f, 0.f, 0.f);
                if (node < nN) {
                    const int beg = rowptr[node], end = rowptr[node + 1];
                    int e = beg;
                    for (; e + 7 < end; e += 8) {
                        int si[8];
#pragma unroll
                        for (int j = 0; j < 8; ++j) si[j] = csr_src[e + j];
                        float4 v[8];
#pragma unroll
                        for (int j = 0; j < 8; ++j) v[j] = x4[(size_t)si[j] * 16 + c];
                        acc.x += ((v[0].x + v[1].x) + (v[2].x + v[3].x)) + ((v[4].x + v[5].x) + (v[6].x + v[7].x));
                        acc.y += ((v[0].y + v[1].y) + (v[2].y + v[3].y)) + ((v[4].y + v[5].y) + (v[6].y + v[7].y));
                        acc.z += ((v[0].z + v[1].z) + (v[2].z + v[3].z)) + ((v[4].z + v[5].z) + (v[6].z + v[7].z));
                        acc.w += ((v[0].w + v[1].w) + (v[2].w + v[3].w)) + ((v[4].w + v[5].w) + (v[6].w + v[7].w));
                    }
                    for (; e < end; ++e) {
                        int s0 = csr_src[e];
                        float4 v0 = x4[(size_t)s0 * 16 + c];
                        acc.x += v0.x; acc.y += v0.y; acc.z += v0.z; acc.w += v0.w;
                    }
                    const float sc = 1.0f / (float)max(end - beg, 1);
                    acc.x *= sc; acc.y *= sc; acc.z *= sc; acc.w *= sc;
                }
                *reinterpret_cast<float4*>(&tile[nl * 68 + c * 4]) = acc;
            }
        }
        __syncthreads();
        {   // MFMA 64x128, K=128
            const int w = tid >> 6, lane = tid & 63;
            const int rloc = w * 16 + (lane & 15);
            const int arow = min(node0 + rloc, nN - 1);
            const int kg = lane >> 4;
            bf8 ahi[4], alo[4];
#pragma unroll
            for (int kc = 0; kc < 2; ++kc) {
                const float* tp = &tile[rloc * 68 + kc * 32 + kg * 8];
                split8(*reinterpret_cast<const float4*>(tp),
                       *reinterpret_cast<const float4*>(tp + 4), ahi[kc], alo[kc]);
            }
#pragma unroll
            for (int kc = 2; kc < 4; ++kc) {
                const float* rp = h1 + (size_t)arow * 64 + (kc - 2) * 32 + kg * 8;
                split8(*reinterpret_cast<const float4*>(rp),
                       *reinterpret_cast<const float4*>(rp + 4), ahi[kc], alo[kc]);
            }
#pragma unroll
            for (int ct = 0; ct < 8; ++ct) {
                const int sec = ct >> 2, ctl = ct & 3;
                const bf8* bgl = reinterpret_cast<const bf8*>(wprep) + 1024 + sec * 2048;
                f32x4 acc = {0.f, 0.f, 0.f, 0.f};
#pragma unroll
                for (int kc = 0; kc < 4; ++kc) {
                    const bf8 bhi = bgl[((ctl * 4 + kc) * 2 + 0) * 64 + lane];
                    const bf8 blo = bgl[((ctl * 4 + kc) * 2 + 1) * 64 + lane];
                    acc = __builtin_amdgcn_mfma_f32_16x16x32_bf16(ahi[kc], bhi, acc, 0, 0, 0);
                    acc = __builtin_amdgcn_mfma_f32_16x16x32_bf16(ahi[kc], blo, acc, 0, 0, 0);
                    acc = __builtin_amdgcn_mfma_f32_16x16x32_bf16(alo[kc], bhi, acc, 0, 0, 0);
                }
                const int col = ct * 16 + (lane & 15);
                const float bv = b2[col];
#pragma unroll
                for (int r = 0; r < 4; ++r) {
                    const int node = node0 + w * 16 + (lane >> 4) * 4 + r;
                    if (node < nN) h2[(size_t)node * 128 + col] = fmaxf(acc[r] + bv, 0.f);
                }
            }
        }
        __syncthreads();
    }
    grid.sync();

    // ============ phase 6: layer 3 dual GEMM (t3 = h2@w3l; r3 = h2@w3r+b3) =
    for (int tk = bid; tk < 2 * ntiles; tk += nblk) {
        const int sel = tk & 1;
        const int node0 = (tk >> 1) * 64;
        const int w = tid >> 6, lane = tid & 63;
        const int arow = min(node0 + w * 16 + (lane & 15), nN - 1);
        const int kg = lane >> 4;
        bf8 ahi[4], alo[4];
#pragma unroll
        for (int kc = 0; kc < 4; ++kc) {
            const float* rp = h2 + (size_t)arow * 128 + kc * 32 + kg * 8;
            split8(*reinterpret_cast<const float4*>(rp),
                   *reinterpret_cast<const float4*>(rp + 4), ahi[kc], alo[kc]);
        }
        const bf8* bgl = reinterpret_cast<const bf8*>(wprep) + 5120 + sel * 2048;
        float* outp = sel ? r3 : t3;
#pragma unroll
        for (int ct = 0; ct < 4; ++ct) {
            f32x4 acc = {0.f, 0.f, 0.f, 0.f};
#pragma unroll
            for (int kc = 0; kc < 4; ++kc) {
                const bf8 bhi = bgl[((ct * 4 + kc) * 2 + 0) * 64 + lane];
                const bf8 blo = bgl[((ct * 4 + kc) * 2 + 1) * 64 + lane];
                acc = __builtin_amdgcn_mfma_f32_16x16x32_bf16(ahi[kc], bhi, acc, 0, 0, 0);
                acc = __builtin_amdgcn_mfma_f32_16x16x32_bf16(ahi[kc], blo, acc, 0, 0, 0);
                acc = __builtin_amdgcn_mfma_f32_16x16x32_bf16(alo[kc], bhi, acc, 0, 0, 0);
            }
            const int col = ct * 16 + (lane & 15);
            const float bv = sel ? b3[col] : 0.f;
#pragma unroll
            for (int r = 0; r < 4; ++r) {
                const int node = node0 + w * 16 + (lane >> 4) * 4 + r;
                if (node < nN) outp[(size_t)node * 64 + col] = acc[r] + bv;
            }
        }
    }
    grid.sync();

    // ============ phase 7: final gather: out = r3 + mean(t3) ==============
    {
        const int ng7 = (nN + 15) >> 4;
        const float4* t34 = reinterpret_cast<const float4*>(t3);
        const float4* r34 = reinterpret_cast<const float4*>(r3);
        float4* o4 = reinterpret_cast<float4*>(dout);
        for (int g = bid; g < ng7; g += nblk) {
            const int node = g * 16 + (tid >> 4);
            const int c = tid & 15;
            if (node >= nN) continue;
            const int beg = rowptr[node], end = rowptr[node + 1];
            float4 acc = make_float4(0.f, 0.f, 0.f, 0.f);
            int e = beg;
            for (; e + 7 < end; e += 8) {
                int si[8];
#pragma unroll
                for (int j = 0; j < 8; ++j) si[j] = csr_src[e + j];
                float4 v[8];
#pragma unroll
                for (int j = 0; j < 8; ++j) v[j] = t34[(size_t)si[j] * 16 + c];
                acc.x += ((v[0].x + v[1].x) + (v[2].x + v[3].x)) + ((v[4].x + v[5].x) + (v[6].x + v[7].x));
                acc.y += ((v[0].y + v[1].y) + (v[2].y + v[3].y)) + ((v[4].y + v[5].y) + (v[6].y + v[7].y));
                acc.z += ((v[0].z + v[1].z) + (v[2].z + v[3].z)) + ((v[4].z + v[5].z) + (v[6].z + v[7].z));
                acc.w += ((v[0].w + v[1].w) + (v[2].w + v[3].w)) + ((v[4].w + v[5].w) + (v[6].w + v[7].w));
            }
            for (; e < end; ++e) {
                int s0 = csr_src[e];
                float4 v0 = t34[(size_t)s0 * 16 + c];
                acc.x += v0.x; acc.y += v0.y; acc.z += v0.z; acc.w += v0.w;
            }
            const float sc = 1.0f / (float)max(end - beg, 1);
            const float4 a = r34[(size_t)node * 16 + c];
            float4 o;
            o.x = fmaf(acc.x, sc, a.x);
            o.y = fmaf(acc.y, sc, a.y);
            o.z = fmaf(acc.z, sc, a.z);
            o.w = fmaf(acc.w, sc, a.w);
            o4[(size_t)node * 16 + c] = o;
        }
    }
}

extern "C" void kernel_launch(void* const* d_in, const int* in_sizes, int n_in,
                              void* d_out, int out_size, void* d_ws, size_t ws_size,
                              hipStream_t stream) {
    const float* x   = (const float*)d_in[0];
    const int*   ei  = (const int*)d_in[1];
    const float* w1l = (const float*)d_in[2];
    const float* b1  = (const float*)d_in[3];
    const float* w1r = (const float*)d_in[4];
    const float* w2l = (const float*)d_in[5];
    const float* b2  = (const float*)d_in[6];
    const float* w2r = (const float*)d_in[7];
    const float* w3l = (const float*)d_in[8];
    const float* b3  = (const float*)d_in[9];
    const float* w3r = (const float*)d_in[10];

    int nN = in_sizes[0] / 32;   // 50000
    int nE = in_sizes[1] / 2;    // 640000

    char* ws = (char*)d_ws;
    size_t o = 0;
    auto alloc = [&](size_t nbytes) {
        char* p = ws + o;
        o += (nbytes + 255) & ~(size_t)255;
        return p;
    };
    int*    cnt      = (int*)alloc(((size_t)nN * 2 + 64) * sizeof(int)); // cnt + cursor
    int*    cursor   = cnt + nN + 32;
    int*    partials = (int*)alloc(64 * sizeof(int));
    int*    rowptr   = (int*)alloc(((size_t)nN + 1) * sizeof(int));
    int*    csr_src  = (int*)alloc((size_t)nE * sizeof(int));
    ushort* wprep    = (ushort*)alloc((size_t)9216 * 8 * sizeof(ushort)); // 144KB
    float*  h1       = (float*)alloc((size_t)nN * 64 * sizeof(float));   // also t3
    float*  h2       = (float*)alloc((size_t)nN * 128 * sizeof(float));
    float*  r3       = (float*)alloc((size_t)nN * 64 * sizeof(float));
    float*  dout     = (float*)d_out;

    int occ = 0;
    hipOccupancyMaxActiveBlocksPerMultiprocessor(&occ, mega_kernel, 256, 0);
    if (occ < 1) occ = 1;
    int grid = occ * 256;                // 256 CUs on MI355X
    if (grid > 2048) grid = 2048;

    void* args[] = {
        (void*)&x, (void*)&ei,
        (void*)&w1l, (void*)&b1, (void*)&w1r,
        (void*)&w2l, (void*)&b2, (void*)&w2r,
        (void*)&w3l, (void*)&b3, (void*)&w3r,
        (void*)&dout,
        (void*)&cnt, (void*)&cursor, (void*)&partials, (void*)&rowptr, (void*)&csr_src,
        (void*)&wprep, (void*)&h1, (void*)&h2, (void*)&r3,
        (void*)&nN, (void*)&nE,
    };
    hipLaunchCooperativeKernel((const void*)mega_kernel, dim3(grid), dim3(256),
                               args, 0, stream);
}

// Round 9
// 140.717 us; speedup vs baseline: 5.0513x; 5.0513x over previous
//
#include <hip/hip_runtime.h>

// ---------------------------------------------------------------------------
// GraphSAGE 3-layer encoder. N=50000, E=640000, ch 32 -> 64 -> 128 -> 64.
// R9: revert R8 coop mega-kernel (grid.sync killed XCD L2 locality: 1145us).
// R7 structure + gather sources stored in bf16 (halves gather bytes+requests):
//   xh = bf16(x); h1 stored as hi/lo bf16 planes (hi gathered, hi+lo = exact
//   split operand for self path); t3 stored bf16 (no downstream matmul).
// fill_kernel de-atomicized: count pass records pos[e]; fill is pure writes.
// GEMM math unchanged: split-bf16 MFMA (hi*hi + hi*lo + lo*hi, fp32 acc).
// ---------------------------------------------------------------------------

typedef short bf8 __attribute__((ext_vector_type(8)));   // 8 bf16 in 4 VGPR
typedef float f32x4 __attribute__((ext_vector_type(4)));

__device__ inline ushort bf16rn(float f) {               // round-to-nearest-even
    unsigned u = __float_as_uint(f);
    return (ushort)((u + 0x7FFFu + ((u >> 16) & 1u)) >> 16);
}
__device__ inline float bf16tof(ushort h) {
    return __uint_as_float(((unsigned)h) << 16);
}
__device__ inline void split8(const float4 pa, const float4 pb, bf8& hi, bf8& lo) {
    const float v[8] = {pa.x, pa.y, pa.z, pa.w, pb.x, pb.y, pb.z, pb.w};
#pragma unroll
    for (int j = 0; j < 8; ++j) {
        const ushort h = bf16rn(v[j]);
        hi[j] = (short)h;
        lo[j] = (short)bf16rn(v[j] - bf16tof(h));
    }
}

// ---- prep: weight hi/lo fragments + zero cnt + x -> bf16 ------------------
__global__ __launch_bounds__(256) void prep_kernel(
    const float* __restrict__ x,
    const float* __restrict__ w1l, const float* __restrict__ w1r,
    const float* __restrict__ w2l, const float* __restrict__ w2r,
    const float* __restrict__ w3l, const float* __restrict__ w3r,
    ushort* __restrict__ wprep, int* __restrict__ cnt,
    ushort* __restrict__ xh, int nN, int nCntZero)
{
    const int g = blockIdx.x * 256 + threadIdx.x;
    const int n = gridDim.x * 256;
    for (int f = g; f < 9216; f += n) {
        int base, KCs, oc0, d0, wstride;
        const float *wa, *wb;
        if (f < 1024)      { base = 0;    KCs = 2; oc0 = 0;  wa = w1l; wb = w1r; d0 = 32;  wstride = 64;  }
        else if (f < 3072) { base = 1024; KCs = 4; oc0 = 0;  wa = w2l; wb = w2r; d0 = 64;  wstride = 128; }
        else if (f < 5120) { base = 3072; KCs = 4; oc0 = 64; wa = w2l; wb = w2r; d0 = 64;  wstride = 128; }
        else if (f < 7168) { base = 5120; KCs = 4; oc0 = 0;  wa = w3l; wb = w3l; d0 = 128; wstride = 64;  }
        else               { base = 7168; KCs = 4; oc0 = 0;  wa = w3r; wb = w3r; d0 = 128; wstride = 64;  }
        const int local = f - base;
        const int lane = local & 63;
        const int s = (local >> 6) & 1;
        const int kcct = local >> 7;
        const int kc = kcct % KCs;
        const int ct = kcct / KCs;
        const int col = oc0 + ct * 16 + (lane & 15);
        const int k0 = kc * 32 + (lane >> 4) * 8;
        ushort h8[8];
#pragma unroll
        for (int j = 0; j < 8; ++j) {
            const int k = k0 + j;
            const float* wr = (k < d0) ? (wa + (size_t)k * wstride)
                                       : (wb + (size_t)(k - d0) * wstride);
            const float v = wr[col];
            const ushort h = bf16rn(v);
            h8[j] = (s == 0) ? h : bf16rn(v - bf16tof(h));
        }
        *reinterpret_cast<int4*>(wprep + (size_t)f * 8) = *reinterpret_cast<const int4*>(h8);
    }
    for (int i = g; i < nCntZero / 4; i += n)
        reinterpret_cast<int4*>(cnt)[i] = make_int4(0, 0, 0, 0);
    const int nxv = nN * 4;                       // 8-element groups of x
    for (int i = g; i < nxv; i += n) {
        const float4 a = reinterpret_cast<const float4*>(x)[i * 2 + 0];
        const float4 b = reinterpret_cast<const float4*>(x)[i * 2 + 1];
        const float v[8] = {a.x, a.y, a.z, a.w, b.x, b.y, b.z, b.w};
        bf8 h;
#pragma unroll
        for (int j = 0; j < 8; ++j) h[j] = (short)bf16rn(v[j]);
        reinterpret_cast<bf8*>(xh)[i] = h;
    }
}

// ---- count: degree + per-edge slot ----------------------------------------
__global__ __launch_bounds__(256) void count_kernel(const int* __restrict__ dst,
                                                    int* __restrict__ cnt,
                                                    int* __restrict__ pos, int nE) {
    int i = blockIdx.x * blockDim.x + threadIdx.x;
    int e0 = i * 4;
    if (e0 + 3 < nE) {
        int4 d = *reinterpret_cast<const int4*>(dst + e0);
        int4 p;
        p.x = atomicAdd(&cnt[d.x], 1);
        p.y = atomicAdd(&cnt[d.y], 1);
        p.z = atomicAdd(&cnt[d.z], 1);
        p.w = atomicAdd(&cnt[d.w], 1);
        *reinterpret_cast<int4*>(pos + e0) = p;
    } else {
        for (int e = e0; e < nE; ++e) pos[e] = atomicAdd(&cnt[dst[e]], 1);
    }
}

__global__ __launch_bounds__(256) void scan_blocks(const int* __restrict__ cnt,
                                                   int* __restrict__ rowptr,
                                                   int* __restrict__ partials, int nN) {
    __shared__ int wsum[4];
    const int t = threadIdx.x;
    const int lane = t & 63, wid = t >> 6;
    const int base = blockIdx.x * 1024 + t * 4;

    int4 v = make_int4(0, 0, 0, 0);
    if (base + 3 < nN) {
        v = *reinterpret_cast<const int4*>(cnt + base);
    } else {
        if (base + 0 < nN) v.x = cnt[base + 0];
        if (base + 1 < nN) v.y = cnt[base + 1];
        if (base + 2 < nN) v.z = cnt[base + 2];
        if (base + 3 < nN) v.w = cnt[base + 3];
    }
    const int s = v.x + v.y + v.z + v.w;

    int inc = s;
#pragma unroll
    for (int d = 1; d < 64; d <<= 1) {
        int u = __shfl_up(inc, d);
        if (lane >= d) inc += u;
    }
    if (lane == 63) wsum[wid] = inc;
    __syncthreads();
    int woff = 0;
#pragma unroll
    for (int w = 0; w < 4; ++w) woff += (w < wid) ? wsum[w] : 0;

    const int excl = woff + inc - s;
    int4 o;
    o.x = excl; o.y = excl + v.x; o.z = excl + v.x + v.y; o.w = excl + v.x + v.y + v.z;
    if (base + 3 < nN) {
        *reinterpret_cast<int4*>(rowptr + base) = o;
    } else {
        if (base + 0 < nN) rowptr[base + 0] = o.x;
        if (base + 1 < nN) rowptr[base + 1] = o.y;
        if (base + 2 < nN) rowptr[base + 2] = o.z;
        if (base + 3 < nN) rowptr[base + 3] = o.w;
    }
    if (t == 255) partials[blockIdx.x] = woff + inc;
}

__global__ __launch_bounds__(256) void scan_add(int* __restrict__ rowptr,
                                                const int* __restrict__ partials,
                                                int nN, int nE) {
    __shared__ int soff;
    const int t = threadIdx.x;
    if (t < 64) {
        int v = (t < blockIdx.x) ? partials[t] : 0;   // grid <= 64 blocks
#pragma unroll
        for (int d = 32; d >= 1; d >>= 1) v += __shfl_xor(v, d);
        if (t == 0) soff = v;
    }
    __syncthreads();
    const int off = soff;
    const int base = blockIdx.x * 1024 + t * 4;
    if (base + 3 < nN) {
        int4 v = *reinterpret_cast<int4*>(rowptr + base);
        v.x += off; v.y += off; v.z += off; v.w += off;
        *reinterpret_cast<int4*>(rowptr + base) = v;
    } else {
        if (base + 0 < nN) rowptr[base + 0] += off;
        if (base + 1 < nN) rowptr[base + 1] += off;
        if (base + 2 < nN) rowptr[base + 2] += off;
        if (base + 3 < nN) rowptr[base + 3] += off;
    }
    if (blockIdx.x == 0 && t == 0) rowptr[nN] = nE;
}

// ---- fill: pure permutation write (no atomics) ----------------------------
__global__ __launch_bounds__(256) void fill_kernel(const int* __restrict__ src,
                                                   const int* __restrict__ dst,
                                                   const int* __restrict__ pos,
                                                   const int* __restrict__ rowptr,
                                                   int* __restrict__ csr_src, int nE) {
    int i = blockIdx.x * blockDim.x + threadIdx.x;
    int e0 = i * 4;
    if (e0 + 3 < nE) {
        int4 s4 = *reinterpret_cast<const int4*>(src + e0);
        int4 d4 = *reinterpret_cast<const int4*>(dst + e0);
        int4 p4 = *reinterpret_cast<const int4*>(pos + e0);
        csr_src[rowptr[d4.x] + p4.x] = s4.x;
        csr_src[rowptr[d4.y] + p4.y] = s4.y;
        csr_src[rowptr[d4.z] + p4.z] = s4.z;
        csr_src[rowptr[d4.w] + p4.w] = s4.w;
    } else {
        for (int e = e0; e < nE; ++e)
            csr_src[rowptr[dst[e]] + pos[e]] = src[e];
    }
}

// ---- layer 1 fused: h1(hi/lo) = relu([mean(xh)|x] @ [w1l;w1r] + b1) -------
__global__ __launch_bounds__(256) void fused_layer1(
    const float* __restrict__ x, const ushort* __restrict__ xh,
    const int* __restrict__ rowptr, const int* __restrict__ csr_src,
    const ushort* __restrict__ wfrag, const float* __restrict__ b1,
    ushort* __restrict__ h1h, ushort* __restrict__ h1l, int nN)
{
    __shared__ float tile[64 * 36];          // 9216 B
    __shared__ ushort wlds[1024 * 8];        // 16 KB

    const int tid = threadIdx.x;
    const int node0 = blockIdx.x * 64;

    {   // stage L1 weights
        const int4* wsrc = reinterpret_cast<const int4*>(wfrag);
        int4* wl = reinterpret_cast<int4*>(wlds);
        for (int i = tid; i < 1024; i += 256) wl[i] = wsrc[i];
    }
    {   // gather mean(xh): 4 lanes/node x 8 elems, all 64 nodes in one pass
        const int nl = tid >> 2;
        const int c = tid & 3;
        const int node = node0 + nl;
        float acc[8] = {0.f, 0.f, 0.f, 0.f, 0.f, 0.f, 0.f, 0.f};
        if (node < nN) {
            const int beg = rowptr[node], end = rowptr[node + 1];
            int e = beg;
            for (; e + 7 < end; e += 8) {
                int si[8];
#pragma unroll
                for (int j = 0; j < 8; ++j) si[j] = csr_src[e + j];
                bf8 v[8];
#pragma unroll
                for (int j = 0; j < 8; ++j)
                    v[j] = *reinterpret_cast<const bf8*>(xh + (size_t)si[j] * 32 + c * 8);
#pragma unroll
                for (int k = 0; k < 8; ++k)
#pragma unroll
                    for (int j = 0; j < 8; ++j) acc[k] += bf16tof((ushort)v[j][k]);
            }
            for (; e < end; ++e) {
                bf8 v = *reinterpret_cast<const bf8*>(xh + (size_t)csr_src[e] * 32 + c * 8);
#pragma unroll
                for (int k = 0; k < 8; ++k) acc[k] += bf16tof((ushort)v[k]);
            }
            const float sc = 1.0f / (float)max(end - beg, 1);
#pragma unroll
            for (int k = 0; k < 8; ++k) acc[k] *= sc;
        }
        *reinterpret_cast<float4*>(&tile[nl * 36 + c * 8 + 0]) =
            make_float4(acc[0], acc[1], acc[2], acc[3]);
        *reinterpret_cast<float4*>(&tile[nl * 36 + c * 8 + 4]) =
            make_float4(acc[4], acc[5], acc[6], acc[7]);
    }
    __syncthreads();

    // ---- MFMA 64x64, K=64
    const int w = tid >> 6, lane = tid & 63;
    const int rloc = w * 16 + (lane & 15);
    const int arow = min(node0 + rloc, nN - 1);
    const int kg = lane >> 4;
    bf8 ahi[2], alo[2];
    {
        const float* tp = &tile[rloc * 36 + kg * 8];
        split8(*reinterpret_cast<const float4*>(tp),
               *reinterpret_cast<const float4*>(tp + 4), ahi[0], alo[0]);
    }
    {
        const float* rp = x + (size_t)arow * 32 + kg * 8;
        split8(*reinterpret_cast<const float4*>(rp),
               *reinterpret_cast<const float4*>(rp + 4), ahi[1], alo[1]);
    }
    const bf8* bgl = reinterpret_cast<const bf8*>(wlds);
#pragma unroll
    for (int ct = 0; ct < 4; ++ct) {
        f32x4 acc = {0.f, 0.f, 0.f, 0.f};
#pragma unroll
        for (int kc = 0; kc < 2; ++kc) {
            const bf8 bhi = bgl[((ct * 2 + kc) * 2 + 0) * 64 + lane];
            const bf8 blo = bgl[((ct * 2 + kc) * 2 + 1) * 64 + lane];
            acc = __builtin_amdgcn_mfma_f32_16x16x32_bf16(ahi[kc], bhi, acc, 0, 0, 0);
            acc = __builtin_amdgcn_mfma_f32_16x16x32_bf16(ahi[kc], blo, acc, 0, 0, 0);
            acc = __builtin_amdgcn_mfma_f32_16x16x32_bf16(alo[kc], bhi, acc, 0, 0, 0);
        }
        const int col = ct * 16 + (lane & 15);
        const float bv = b1[col];
#pragma unroll
        for (int r = 0; r < 4; ++r) {
            const int node = node0 + w * 16 + (lane >> 4) * 4 + r;
            if (node < nN) {
                const float o = fmaxf(acc[r] + bv, 0.f);
                const ushort hi = bf16rn(o);
                h1h[(size_t)node * 64 + col] = hi;
                h1l[(size_t)node * 64 + col] = bf16rn(o - bf16tof(hi));
            }
        }
    }
}

// ---- layer 2 fused: h2 = relu([mean(h1h)|h1] @ [w2l;w2r] + b2) ------------
__global__ __launch_bounds__(256) void fused_layer2(
    const ushort* __restrict__ h1h, const ushort* __restrict__ h1l,
    const int* __restrict__ rowptr, const int* __restrict__ csr_src,
    const ushort* __restrict__ wfrag, const float* __restrict__ b2,
    float* __restrict__ h2, int nN)
{
    __shared__ float tile[64 * 68];          // 17408 B

    const int tid = threadIdx.x;
    const int node0 = blockIdx.x * 64;

    {   // gather mean(h1h): 8 lanes/node x 8 elems, 2 passes
        const int c = tid & 7;
        const int nl0 = tid >> 3;
#pragma unroll
        for (int p = 0; p < 2; ++p) {
            const int nl = p * 32 + nl0;
            const int node = node0 + nl;
            float acc[8] = {0.f, 0.f, 0.f, 0.f, 0.f, 0.f, 0.f, 0.f};
            if (node < nN) {
                const int beg = rowptr[node], end = rowptr[node + 1];
                int e = beg;
                for (; e + 7 < end; e += 8) {
                    int si[8];
#pragma unroll
                    for (int j = 0; j < 8; ++j) si[j] = csr_src[e + j];
                    bf8 v[8];
#pragma unroll
                    for (int j = 0; j < 8; ++j)
                        v[j] = *reinterpret_cast<const bf8*>(h1h + (size_t)si[j] * 64 + c * 8);
#pragma unroll
                    for (int k = 0; k < 8; ++k)
#pragma unroll
                        for (int j = 0; j < 8; ++j) acc[k] += bf16tof((ushort)v[j][k]);
                }
                for (; e < end; ++e) {
                    bf8 v = *reinterpret_cast<const bf8*>(h1h + (size_t)csr_src[e] * 64 + c * 8);
#pragma unroll
                    for (int k = 0; k < 8; ++k) acc[k] += bf16tof((ushort)v[k]);
                }
                const float sc = 1.0f / (float)max(end - beg, 1);
#pragma unroll
                for (int k = 0; k < 8; ++k) acc[k] *= sc;
            }
            *reinterpret_cast<float4*>(&tile[nl * 68 + c * 8 + 0]) =
                make_float4(acc[0], acc[1], acc[2], acc[3]);
            *reinterpret_cast<float4*>(&tile[nl * 68 + c * 8 + 4]) =
                make_float4(acc[4], acc[5], acc[6], acc[7]);
        }
    }
    __syncthreads();

    // ---- MFMA 64x128, K=128
    const int w = tid >> 6, lane = tid & 63;
    const int rloc = w * 16 + (lane & 15);
    const int arow = min(node0 + rloc, nN - 1);
    const int kg = lane >> 4;
    bf8 ahi[4], alo[4];
#pragma unroll
    for (int kc = 0; kc < 2; ++kc) {
        const float* tp = &tile[rloc * 68 + kc * 32 + kg * 8];
        split8(*reinterpret_cast<const float4*>(tp),
               *reinterpret_cast<const float4*>(tp + 4), ahi[kc], alo[kc]);
    }
#pragma unroll
    for (int kc = 2; kc < 4; ++kc) {    // self: hi/lo planes ARE the split
        const size_t off = (size_t)arow * 64 + (kc - 2) * 32 + kg * 8;
        ahi[kc] = *reinterpret_cast<const bf8*>(h1h + off);
        alo[kc] = *reinterpret_cast<const bf8*>(h1l + off);
    }
#pragma unroll
    for (int ct = 0; ct < 8; ++ct) {
        const int sec = ct >> 2, ctl = ct & 3;
        const bf8* bgl = reinterpret_cast<const bf8*>(wfrag) + sec * 2048;
        f32x4 acc = {0.f, 0.f, 0.f, 0.f};
#pragma unroll
        for (int kc = 0; kc < 4; ++kc) {
            const bf8 bhi = bgl[((ctl * 4 + kc) * 2 + 0) * 64 + lane];
            const bf8 blo = bgl[((ctl * 4 + kc) * 2 + 1) * 64 + lane];
            acc = __builtin_amdgcn_mfma_f32_16x16x32_bf16(ahi[kc], bhi, acc, 0, 0, 0);
            acc = __builtin_amdgcn_mfma_f32_16x16x32_bf16(ahi[kc], blo, acc, 0, 0, 0);
            acc = __builtin_amdgcn_mfma_f32_16x16x32_bf16(alo[kc], bhi, acc, 0, 0, 0);
        }
        const int col = ct * 16 + (lane & 15);
        const float bv = b2[col];
#pragma unroll
        for (int r = 0; r < 4; ++r) {
            const int node = node0 + w * 16 + (lane >> 4) * 4 + r;
            if (node < nN) h2[(size_t)node * 128 + col] = fmaxf(acc[r] + bv, 0.f);
        }
    }
}

// ---- layer 3 dual GEMM: t3h = bf16(h2@w3l); r3 = h2@w3r + b3 --------------
__global__ __launch_bounds__(256) void mfma_dual(
    const float* __restrict__ h2, const ushort* __restrict__ wfrag,
    const float* __restrict__ b3, ushort* __restrict__ t3h,
    float* __restrict__ r3, int nN)
{
    __shared__ ushort wlds[2048 * 8];        // 32 KB

    const int tid = threadIdx.x;
    const int sel = blockIdx.y;
    {
        const int4* wsrc = reinterpret_cast<const int4*>(wfrag) + (size_t)sel * 2048;
        int4* wl = reinterpret_cast<int4*>(wlds);
        for (int i = tid; i < 2048; i += 256) wl[i] = wsrc[i];
    }
    __syncthreads();

    const int w = tid >> 6, lane = tid & 63;
    const int node0 = blockIdx.x * 64;
    const int arow = min(node0 + w * 16 + (lane & 15), nN - 1);
    const int kg = lane >> 4;
    bf8 ahi[4], alo[4];
#pragma unroll
    for (int kc = 0; kc < 4; ++kc) {
        const float* rp = h2 + (size_t)arow * 128 + kc * 32 + kg * 8;
        split8(*reinterpret_cast<const float4*>(rp),
               *reinterpret_cast<const float4*>(rp + 4), ahi[kc], alo[kc]);
    }
    const bf8* bgl = reinterpret_cast<const bf8*>(wlds);
#pragma unroll
    for (int ct = 0; ct < 4; ++ct) {
        f32x4 acc = {0.f, 0.f, 0.f, 0.f};
#pragma unroll
        for (int kc = 0; kc < 4; ++kc) {
            const bf8 bhi = bgl[((ct * 4 + kc) * 2 + 0) * 64 + lane];
            const bf8 blo = bgl[((ct * 4 + kc) * 2 + 1) * 64 + lane];
            acc = __builtin_amdgcn_mfma_f32_16x16x32_bf16(ahi[kc], bhi, acc, 0, 0, 0);
            acc = __builtin_amdgcn_mfma_f32_16x16x32_bf16(ahi[kc], blo, acc, 0, 0, 0);
            acc = __builtin_amdgcn_mfma_f32_16x16x32_bf16(alo[kc], bhi, acc, 0, 0, 0);
        }
        const int col = ct * 16 + (lane & 15);
#pragma unroll
        for (int r = 0; r < 4; ++r) {
            const int node = node0 + w * 16 + (lane >> 4) * 4 + r;
            if (node < nN) {
                if (sel) r3[(size_t)node * 64 + col] = acc[r] + b3[col];
                else     t3h[(size_t)node * 64 + col] = bf16rn(acc[r]);
            }
        }
    }
}

// ---- final: out = r3 + mean(t3h) ------------------------------------------
__global__ __launch_bounds__(256) void final_gather(
    const ushort* __restrict__ t3h, const int* __restrict__ rowptr,
    const int* __restrict__ csr_src, const float* __restrict__ r3,
    float* __restrict__ dout, int nN)
{
    const int tid = threadIdx.x;
    const int node = blockIdx.x * 32 + (tid >> 3);
    const int c = tid & 7;
    if (node >= nN) return;
    const int beg = rowptr[node], end = rowptr[node + 1];
    float acc[8] = {0.f, 0.f, 0.f, 0.f, 0.f, 0.f, 0.f, 0.f};
    int e = beg;
    for (; e + 7 < end; e += 8) {
        int si[8];
#pragma unroll
        for (int j = 0; j < 8; ++j) si[j] = csr_src[e + j];
        bf8 v[8];
#pragma unroll
        for (int j = 0; j < 8; ++j)
            v[j] = *reinterpret_cast<const bf8*>(t3h + (size_t)si[j] * 64 + c * 8);
#pragma unroll
        for (int k = 0; k < 8; ++k)
#pragma unroll
            for (int j = 0; j < 8; ++j) acc[k] += bf16tof((ushort)v[j][k]);
    }
    for (; e < end; ++e) {
        bf8 v = *reinterpret_cast<const bf8*>(t3h + (size_t)csr_src[e] * 64 + c * 8);
#pragma unroll
        for (int k = 0; k < 8; ++k) acc[k] += bf16tof((ushort)v[k]);
    }
    const float sc = 1.0f / (float)max(end - beg, 1);
    const float4 a0 = reinterpret_cast<const float4*>(r3)[(size_t)node * 16 + c * 2 + 0];
    const float4 a1 = reinterpret_cast<const float4*>(r3)[(size_t)node * 16 + c * 2 + 1];
    float4 o0, o1;
    o0.x = fmaf(acc[0], sc, a0.x); o0.y = fmaf(acc[1], sc, a0.y);
    o0.z = fmaf(acc[2], sc, a0.z); o0.w = fmaf(acc[3], sc, a0.w);
    o1.x = fmaf(acc[4], sc, a1.x); o1.y = fmaf(acc[5], sc, a1.y);
    o1.z = fmaf(acc[6], sc, a1.z); o1.w = fmaf(acc[7], sc, a1.w);
    reinterpret_cast<float4*>(dout)[(size_t)node * 16 + c * 2 + 0] = o0;
    reinterpret_cast<float4*>(dout)[(size_t)node * 16 + c * 2 + 1] = o1;
}

extern "C" void kernel_launch(void* const* d_in, const int* in_sizes, int n_in,
                              void* d_out, int out_size, void* d_ws, size_t ws_size,
                              hipStream_t stream) {
    const float* x   = (const float*)d_in[0];
    const int*   ei  = (const int*)d_in[1];
    const float* w1l = (const float*)d_in[2];
    const float* b1  = (const float*)d_in[3];
    const float* w1r = (const float*)d_in[4];
    const float* w2l = (const float*)d_in[5];
    const float* b2  = (const float*)d_in[6];
    const float* w2r = (const float*)d_in[7];
    const float* w3l = (const float*)d_in[8];
    const float* b3  = (const float*)d_in[9];
    const float* w3r = (const float*)d_in[10];

    const int nN = in_sizes[0] / 32;   // 50000
    const int nE = in_sizes[1] / 2;    // 640000
    const int* src = ei;
    const int* dst = ei + nE;
    const int nB = (nN + 1023) / 1024; // 49 scan blocks (<= 64)
    const int nCntZero = (nN + 63) & ~63;

    char* ws = (char*)d_ws;
    size_t o = 0;
    auto alloc = [&](size_t nbytes) {
        char* p = ws + o;
        o += (nbytes + 255) & ~(size_t)255;
        return p;
    };
    int*    cnt      = (int*)alloc((size_t)nCntZero * sizeof(int));
    int*    pos      = (int*)alloc((size_t)nE * sizeof(int));
    int*    partials = (int*)alloc(64 * sizeof(int));
    int*    rowptr   = (int*)alloc(((size_t)nN + 1) * sizeof(int));
    int*    csr_src  = (int*)alloc((size_t)nE * sizeof(int));
    ushort* wprep    = (ushort*)alloc((size_t)9216 * 8 * sizeof(ushort)); // 144KB
    ushort* xh       = (ushort*)alloc((size_t)nN * 32 * sizeof(ushort));
    ushort* h1h      = (ushort*)alloc((size_t)nN * 64 * sizeof(ushort));
    ushort* h1l      = (ushort*)alloc((size_t)nN * 64 * sizeof(ushort));
    float*  h2       = (float*)alloc((size_t)nN * 128 * sizeof(float));
    ushort* t3h      = (ushort*)alloc((size_t)nN * 64 * sizeof(ushort));
    float*  r3       = (float*)alloc((size_t)nN * 64 * sizeof(float));

    // ---- prep (weights + zero + x->bf16)
    prep_kernel<<<784, 256, 0, stream>>>(x, w1l, w1r, w2l, w2r, w3l, w3r,
                                         wprep, cnt, xh, nN, nCntZero);
    // ---- CSR build
    count_kernel<<<(nE / 4 + 255) / 256, 256, 0, stream>>>(dst, cnt, pos, nE);
    scan_blocks<<<nB, 256, 0, stream>>>(cnt, rowptr, partials, nN);
    scan_add<<<nB, 256, 0, stream>>>(rowptr, partials, nN, nE);
    fill_kernel<<<(nE / 4 + 255) / 256, 256, 0, stream>>>(src, dst, pos, rowptr, csr_src, nE);

    const int xblk = (nN + 63) / 64;   // 782

    // ---- layer 1 fused
    fused_layer1<<<xblk, 256, 0, stream>>>(x, xh, rowptr, csr_src, wprep, b1, h1h, h1l, nN);
    // ---- layer 2 fused
    fused_layer2<<<xblk, 256, 0, stream>>>(h1h, h1l, rowptr, csr_src,
                                           wprep + (size_t)1024 * 8, b2, h2, nN);
    // ---- layer 3 dual + final gather
    mfma_dual<<<dim3(xblk, 2), 256, 0, stream>>>(h2, wprep + (size_t)5120 * 8, b3, t3h, r3, nN);
    final_gather<<<(nN + 31) / 32, 256, 0, stream>>>(t3h, rowptr, csr_src, r3, (float*)d_out, nN);
}